// Round 4
// baseline (48.460 us; speedup 1.0000x reference)
//
#include <hip/hip_runtime.h>

// out[b,s,d] = x[b,s,d] + pe[d], D=1024. Pure streaming add: 128 MiB in,
// 128 MiB out -> memory-bound floor = 268 MB / 6.29 TB/s ~= 43 us.
// Round 3 measured 45.6 us (93.5% of copy ceiling) with unroll x2.
//
// Round-4 change: unroll x4 (4 loads in flight before the 4 stores), grid
// back to 2048 (16 float4s/thread = 4 unrolled iterations). Last MLP lever.
//
// block=256: each thread owns one float4 column of the 1024-wide row; all
// strides are multiples of 256 float4s so the column is invariant per
// thread -> PE computed ONCE per thread in registers (no trig in hot loop).

typedef float v4f __attribute__((ext_vector_type(4)));

__global__ void __launch_bounds__(256)
_PositionalEncoding_60395830117137_kernel(const v4f* __restrict__ x,
                                          v4f* __restrict__ out,
                                          long long n4) {
    const int c = threadIdx.x;  // float4 column: elements 4c..4c+3 of the row

    const float ja = 2.0f * (float)c;
    const float jb = ja + 1.0f;
    const float den_a = powf(10000.0f, ja * (2.0f / 1024.0f));
    const float den_b = powf(10000.0f, jb * (2.0f / 1024.0f));

    v4f pe;
    pe.x = sinf(den_a);
    pe.y = cosf(den_a);
    pe.z = sinf(den_b);
    pe.w = cosf(den_b);

    const long long stride = (long long)gridDim.x * 256;  // multiple of 256
    long long idx = (long long)blockIdx.x * 256 + c;

    // Unrolled x4: 4 outstanding vmem loads per wave iteration.
    for (; idx + 3 * stride < n4; idx += 4 * stride) {
        v4f v0 = x[idx];
        v4f v1 = x[idx + stride];
        v4f v2 = x[idx + 2 * stride];
        v4f v3 = x[idx + 3 * stride];
        v0 += pe;
        v1 += pe;
        v2 += pe;
        v3 += pe;
        out[idx] = v0;
        out[idx + stride] = v1;
        out[idx + 2 * stride] = v2;
        out[idx + 3 * stride] = v3;
    }
    // Tail (not taken for n4 = 8,388,608 with grid 2048, kept for safety).
    for (; idx < n4; idx += stride) {
        v4f v = x[idx];
        v += pe;
        out[idx] = v;
    }
}

extern "C" void kernel_launch(void* const* d_in, const int* in_sizes, int n_in,
                              void* d_out, int out_size, void* d_ws, size_t ws_size,
                              hipStream_t stream) {
    const float* x = (const float*)d_in[0];
    float* out = (float*)d_out;

    const long long n = (long long)in_sizes[0];  // 33,554,432 (multiple of 4)
    const long long n4 = n / 4;

    const int block = 256;
    const int grid = 2048;  // 16 float4s/thread = 4 unrolled iterations of 4

    _PositionalEncoding_60395830117137_kernel<<<grid, block, 0, stream>>>(
        (const v4f*)x, (v4f*)out, n4);
}

// Round 5
// 44.904 us; speedup vs baseline: 1.0792x; 1.0792x over previous
//
#include <hip/hip_runtime.h>

// out[b,s,d] = x[b,s,d] + pe[d], D=1024. Pure streaming add: 128 MiB in,
// 128 MiB out -> memory-bound floor = 268 MB / 6.29 TB/s ~= 43 us.
//
// FINAL (revert to round-3 best, 45.6 us = 93.5% of copy ceiling):
//   - unroll x2, both loads issued before both stores (MLP sweet spot:
//     x1=47.0, x2=45.6, x4=48.5 us -- x4 cost occupancy, VGPR 16->24)
//   - grid 4096 x 256 (8 float4s/thread)
//   - nt stores tested: neutral (FETCH_SIZE unchanged) -> plain stores
//   - PE computed once per thread in registers (column invariant under
//     grid-stride that's a multiple of 256 float4s); no trig in hot loop.

typedef float v4f __attribute__((ext_vector_type(4)));

__global__ void __launch_bounds__(256)
_PositionalEncoding_60395830117137_kernel(const v4f* __restrict__ x,
                                          v4f* __restrict__ out,
                                          long long n4) {
    const int c = threadIdx.x;  // float4 column: elements 4c..4c+3 of the row

    const float ja = 2.0f * (float)c;
    const float jb = ja + 1.0f;
    const float den_a = powf(10000.0f, ja * (2.0f / 1024.0f));
    const float den_b = powf(10000.0f, jb * (2.0f / 1024.0f));

    v4f pe;
    pe.x = sinf(den_a);
    pe.y = cosf(den_a);
    pe.z = sinf(den_b);
    pe.w = cosf(den_b);

    const long long stride = (long long)gridDim.x * 256;  // multiple of 256
    long long idx = (long long)blockIdx.x * 256 + c;

    // Unrolled x2: issue both loads before both stores (2 outstanding vmem
    // loads per wave iteration).
    for (; idx + stride < n4; idx += 2 * stride) {
        v4f v0 = x[idx];
        v4f v1 = x[idx + stride];
        v0 += pe;
        v1 += pe;
        out[idx] = v0;
        out[idx + stride] = v1;
    }
    // Tail (not taken for n4 = 8,388,608 with grid 4096, kept for safety).
    for (; idx < n4; idx += stride) {
        v4f v = x[idx];
        v += pe;
        out[idx] = v;
    }
}

extern "C" void kernel_launch(void* const* d_in, const int* in_sizes, int n_in,
                              void* d_out, int out_size, void* d_ws, size_t ws_size,
                              hipStream_t stream) {
    const float* x = (const float*)d_in[0];
    float* out = (float*)d_out;

    const long long n = (long long)in_sizes[0];  // 33,554,432 (multiple of 4)
    const long long n4 = n / 4;

    const int block = 256;
    const int grid = 4096;  // 1,048,576 threads; 8 float4s/thread (4 unrolled pairs)

    _PositionalEncoding_60395830117137_kernel<<<grid, block, 0, stream>>>(
        (const v4f*)x, (v4f*)out, n4);
}